// Round 7
// baseline (758.923 us; speedup 1.0000x reference)
//
#include <hip/hip_runtime.h>
#include <stdint.h>
#include <math.h>

// ============================================================================
// ProposalDistribution: 4x fp32 GEMM [32768,512]x[512,512]^T -> exp ->
// per-row Gaussian-NLL quadratic coefficients -> JAX-threefry rejection sampler.
//
// R6 -> R7: (1) A-frags (X) load straight from global into regs (fp16-split in
// VALU) -- X LDS staging removed; (2) W DMA double-buffered, ONE barrier per
// round (DMA issued a full round ahead); (3) epilogue partials accumulate in
// registers across colgroups, shuffle-reduce once per dist (8x fewer
// ds_permutes). Rounds: 2 dist x 8 cg(64 cols) x 16 kc(K=32) = 256.
// LDS static: Wp[2][4][64*32] f16 (32 KB) + red[4][64][8] f32 (8 KB) = 40 KB.
// ============================================================================

typedef _Float16 f16;
typedef __attribute__((ext_vector_type(8))) _Float16 f16x8;
typedef __attribute__((ext_vector_type(4))) _Float16 f16x4;
typedef __attribute__((ext_vector_type(4))) float f32x4;

#define SX 16.0f
#define SW 1024.0f
#define INV_S (1.0f / 16384.0f)
#define LOG_EPS (-13.815510557964274f)   // log(1e-6)
#define PLANE 262144                      // 512*512 elements per f16 plane
#define WS_NEED (4u * 2u * PLANE * 2u)    // 4 mats x (hi+lo) x 2B = 4 MB

struct U2 { uint32_t a, b; };

__device__ __forceinline__ uint32_t rotl(uint32_t v, int d) {
  return (v << d) | (v >> (32 - d));
}

// Threefry-2x32, 20 rounds — exact JAX algorithm.
__device__ __forceinline__ U2 tf2x32(uint32_t k0, uint32_t k1, uint32_t x0, uint32_t x1) {
  const uint32_t k2 = k0 ^ k1 ^ 0x1BD11BDAu;
  x0 += k0; x1 += k1;
#define TFR(r) { x0 += x1; x1 = rotl(x1, r); x1 ^= x0; }
  TFR(13) TFR(15) TFR(26) TFR(6)
  x0 += k1; x1 += k2 + 1u;
  TFR(17) TFR(29) TFR(16) TFR(24)
  x0 += k2; x1 += k0 + 2u;
  TFR(13) TFR(15) TFR(26) TFR(6)
  x0 += k0; x1 += k1 + 3u;
  TFR(17) TFR(29) TFR(16) TFR(24)
  x0 += k1; x1 += k2 + 4u;
  TFR(13) TFR(15) TFR(26) TFR(6)
  x0 += k2; x1 += k0 + 5u;
#undef TFR
  U2 r; r.a = x0; r.b = x1; return r;
}

__device__ __forceinline__ float bits_to_u01(uint32_t b) {
  return __uint_as_float((b >> 9) | 0x3f800000u) - 1.0f;
}

// ---------------------------------------------------------------------------
// Pre-kernel: split 4 W matrices (fp32, scaled by 1024) into fp16 hi/lo planes.
// ws layout: mat m -> hi plane at m*2*PLANE, lo plane at +PLANE.
// mats: 0=W_mu_x, 1=W_sg_x, 2=W_mu_y, 3=W_sg_y. Row-major [outcol][k].
// ---------------------------------------------------------------------------
__global__ __launch_bounds__(256) void convert_w_kernel(
    const float* __restrict__ w0, const float* __restrict__ w1,
    const float* __restrict__ w2, const float* __restrict__ w3,
    f16* __restrict__ ws)
{
  const int mat = blockIdx.x >> 8;
  const int idx = (((blockIdx.x & 255) << 8) | threadIdx.x) << 2;
  const float* W = (mat == 0) ? w0 : (mat == 1) ? w1 : (mat == 2) ? w2 : w3;
  float4 v = *(const float4*)(W + idx);
  f16* hi = ws + (size_t)mat * (2 * PLANE) + idx;
  f16* lo = hi + PLANE;
  float a0 = v.x * SW, a1 = v.y * SW, a2 = v.z * SW, a3 = v.w * SW;
  f16 h0 = (f16)a0, h1 = (f16)a1, h2 = (f16)a2, h3 = (f16)a3;
  *(f16x4*)hi = (f16x4){h0, h1, h2, h3};
  *(f16x4*)lo = (f16x4){(f16)(a0 - (float)h0), (f16)(a1 - (float)h1),
                        (f16)(a2 - (float)h2), (f16)(a3 - (float)h3)};
}

// ---------------------------------------------------------------------------
// Main MFMA kernel. 512 blocks x 256 threads (4 waves), 2 blocks/CU.
// Block tile: 64 rows. Round = (dist, cg of 64 cols, kc of K=32), 256 rounds.
// Wave w: cols w*16 (1 col-frag) x 64 rows (4 row-frags), both mats.
// ---------------------------------------------------------------------------
__global__ __launch_bounds__(256, 2)
void mfma_proposal_kernel(const float* __restrict__ gx, const float* __restrict__ gy,
                          const float* __restrict__ bmux, const float* __restrict__ bsgx,
                          const float* __restrict__ bmuy, const float* __restrict__ bsgy,
                          const f16* __restrict__ ws, float* __restrict__ out)
{
  __shared__ f16 Wp[2][4][64 * 32];   // dbuf x planes{mu-hi,mu-lo,sg-hi,sg-lo}, 32 KB
  __shared__ float red[4][64][8];     // per-wave row sums [A,I,M,Q] x 2 dists, 8 KB

  const int tid = threadIdx.x;
  const int lane = tid & 63;
  const int w = tid >> 6;           // wave id -> col slice w*16
  const int ln = lane & 15;         // frag row/col lane
  const int quad = lane >> 4;       // frag k-quad
  const int r0 = blockIdx.x * 64;

  const int dma_sg = (lane & 3) ^ ((lane >> 3) & 3);  // swizzled k-seg for DMA src
  const int dma_col = lane >> 2;                      // col within 16-col chunk

  for (int i = tid; i < 4 * 64 * 8; i += 256) (&red[0][0][0])[i] = 0.0f;

  // Stage W for round 0 into buffer 0 (wave w stages plane w).
#define STAGE_W(RID, BUF) do {                                                   \
    const int kc_ = (RID) & 15, cg_ = ((RID) >> 4) & 7, dist_ = (RID) >> 7;      \
    const f16* plane_ = ws + (size_t)(dist_ * 2 + (w >> 1)) * (2 * PLANE)        \
                           + (size_t)(w & 1) * PLANE;                            \
    const f16* gp_ = plane_ + (size_t)(cg_ * 64 + dma_col) * 512                 \
                            + kc_ * 32 + dma_sg * 8;                             \
    f16* lp_ = &Wp[BUF][w][0];                                                   \
    _Pragma("unroll")                                                            \
    for (int j_ = 0; j_ < 4; ++j_) {                                             \
      __builtin_amdgcn_global_load_lds(                                          \
          (const __attribute__((address_space(1))) void*)(gp_ + (size_t)(j_ * 16) * 512), \
          (__attribute__((address_space(3))) void*)(lp_ + j_ * 16 * 32), 16, 0, 0); \
    }                                                                            \
  } while (0)

  STAGE_W(0, 0);

  f32x4 accm[4], accv[4];     // 1 col-frag x 4 row-frags x 2 mats
  f32x4 ep[4][4];             // per-(ri,g) running [A,I,M,Q] partials over cg
#pragma unroll
  for (int ri = 0; ri < 4; ++ri)
#pragma unroll
    for (int g = 0; g < 4; ++g) ep[ri][g] = (f32x4)0.0f;

  for (int rid = 0; rid < 256; ++rid) {
    const int kc = rid & 15;
    const int cg = (rid >> 4) & 7;
    const int dist = rid >> 7;
    const int buf = rid & 1;

    if (kc == 0) {
#pragma unroll
      for (int ri = 0; ri < 4; ++ri) { accm[ri] = (f32x4)0.0f; accv[ri] = (f32x4)0.0f; }
    }

    __syncthreads();   // closes reads of Wp[buf^1] (round rid-1), drains DMA_rid

    // ---- A-frag loads for THIS round (fp32, direct from global; L1-hot) ----
    // Issued before the DMA so the compiler can wait them with vmcnt(4)
    // while the next round's DMA stays in flight.
    float4 xa[4][2];
    {
      const float* Xg = dist ? gy : gx;
      const float* xb = Xg + (size_t)(r0 + ln) * 512 + kc * 32 + quad * 8;
#pragma unroll
      for (int ri = 0; ri < 4; ++ri) {
        xa[ri][0] = *(const float4*)(xb + (size_t)(ri * 16) * 512);
        xa[ri][1] = *(const float4*)(xb + (size_t)(ri * 16) * 512 + 4);
      }
    }

    // ---- DMA next round's W into the alternate buffer ----
    if (rid + 1 < 256) STAGE_W(rid + 1, buf ^ 1);

    // ---- split A to fp16 hi/lo ----
    f16x8 ah[4], al[4];
#pragma unroll
    for (int ri = 0; ri < 4; ++ri) {
      const float aa[8] = {xa[ri][0].x, xa[ri][0].y, xa[ri][0].z, xa[ri][0].w,
                           xa[ri][1].x, xa[ri][1].y, xa[ri][1].z, xa[ri][1].w};
      f16x8 hv, lv;
#pragma unroll
      for (int i = 0; i < 8; ++i) {
        const float as = aa[i] * SX;
        const f16 hh = (f16)as;
        hv[i] = hh;
        lv[i] = (f16)(as - (float)hh);
      }
      ah[ri] = hv;
      al[ri] = lv;
    }

    // ---- B frags from LDS (swizzled, conflict-free) ----
    const int c_l = w * 16 + ln;
    const int boff = c_l * 32 + ((quad ^ ((c_l >> 1) & 3)) << 3);
    const f16x8 bhm = *(const f16x8*)&Wp[buf][0][boff];
    const f16x8 blm = *(const f16x8*)&Wp[buf][1][boff];
    const f16x8 bhv = *(const f16x8*)&Wp[buf][2][boff];
    const f16x8 blv = *(const f16x8*)&Wp[buf][3][boff];

    // ---- 24 MFMAs ----
#pragma unroll
    for (int ri = 0; ri < 4; ++ri) {
      accm[ri] = __builtin_amdgcn_mfma_f32_16x16x32_f16(al[ri], bhm, accm[ri], 0, 0, 0);
      accm[ri] = __builtin_amdgcn_mfma_f32_16x16x32_f16(ah[ri], blm, accm[ri], 0, 0, 0);
      accm[ri] = __builtin_amdgcn_mfma_f32_16x16x32_f16(ah[ri], bhm, accm[ri], 0, 0, 0);
      accv[ri] = __builtin_amdgcn_mfma_f32_16x16x32_f16(al[ri], bhv, accv[ri], 0, 0, 0);
      accv[ri] = __builtin_amdgcn_mfma_f32_16x16x32_f16(ah[ri], blv, accv[ri], 0, 0, 0);
      accv[ri] = __builtin_amdgcn_mfma_f32_16x16x32_f16(ah[ri], bhv, accv[ri], 0, 0, 0);
    }

    // ---- end of colgroup: fold acc into per-thread ep partials (VALU only) ----
    if (kc == 15) {
      const float* bmu = dist ? bmuy : bmux;
      const float* bsg = dist ? bsgy : bsgx;
      const int col = cg * 64 + w * 16 + ln;
      const float bm_ = bmu[col], bv_ = bsg[col];
#pragma unroll
      for (int ri = 0; ri < 4; ++ri) {
#pragma unroll
        for (int g = 0; g < 4; ++g) {
          const float m = accm[ri][g] * INV_S + bm_;
          const float s = accv[ri][g] * INV_S + bv_;
          const float vv = fmaxf(expf(s), 1e-6f);
          const float iv = __builtin_amdgcn_rcpf(vv);
          ep[ri][g][0] += fmaxf(s, LOG_EPS);
          ep[ri][g][1] += iv;
          ep[ri][g][2] += m * iv;
          ep[ri][g][3] += m * m * iv;
        }
      }
    }

    // ---- end of dist: shuffle-reduce ep over the 16 col-lanes, write red ----
    if ((rid & 127) == 127) {
#pragma unroll
      for (int ri = 0; ri < 4; ++ri) {
#pragma unroll
        for (int g = 0; g < 4; ++g) {
          f32x4 p = ep[ri][g];
#pragma unroll
          for (int msk = 1; msk < 16; msk <<= 1) {
            p[0] += __shfl_xor(p[0], msk);
            p[1] += __shfl_xor(p[1], msk);
            p[2] += __shfl_xor(p[2], msk);
            p[3] += __shfl_xor(p[3], msk);
          }
          if (ln == 0) {
            float* rr = &red[w][ri * 16 + quad * 4 + g][dist * 4];
            rr[0] = p[0]; rr[1] = p[1]; rr[2] = p[2]; rr[3] = p[3];
          }
          ep[ri][g] = (f32x4)0.0f;
        }
      }
    }
  }

  __syncthreads();

  // ---- fused rejection sampler: one thread per row, exact JAX threefry ----
  if (tid < 64) {
    const int grow = r0 + tid;
    double Ax = 0, Ix = 0, Mx = 0, Qx = 0, Ay = 0, Iy = 0, My = 0, Qy = 0;
#pragma unroll
    for (int s = 0; s < 4; ++s) {
      Ax += (double)red[s][tid][0]; Ix += (double)red[s][tid][1];
      Mx += (double)red[s][tid][2]; Qx += (double)red[s][tid][3];
      Ay += (double)red[s][tid][4]; Iy += (double)red[s][tid][5];
      My += (double)red[s][tid][6]; Qy += (double)red[s][tid][7];
    }

    U2 key = tf2x32(0u, 42u, 0u, (uint32_t)grow);   // partitionable split

    float xi = 0.0f;
    bool done = false;
    for (int it = 0; it < 100000 && !done; ++it) {
      const U2 kn = tf2x32(key.a, key.b, 0u, 0u);
      const U2 k1 = tf2x32(key.a, key.b, 0u, 1u);
      const U2 k2 = tf2x32(key.a, key.b, 0u, 2u);
      const U2 ru = tf2x32(k1.a, k1.b, 0u, 0u);
      const U2 rx = tf2x32(k2.a, k2.b, 0u, 0u);
      const float u  = bits_to_u01(ru.a ^ ru.b);
      const float u2 = bits_to_u01(rx.a ^ rx.b);
      xi = 2.0f * u2 - 1.0f;
      const double dxi = (double)xi;
      const double nx = (0.5 / 512.0) * (Ax + Qx + dxi * (dxi * Ix - 2.0 * Mx));
      const double ny = (0.5 / 512.0) * (Ay + Qy + dxi * (dxi * Iy - 2.0 * My));
      done = ((double)u >= nx * ny);
      key = kn;
    }
    out[grow] = fminf(fmaxf(xi, 1e-5f), 10.0f);
  }
#undef STAGE_W
}

// ---------------------------------------------------------------------------
// Fallback: R4's passing fp32-vector kernel (used only if ws_size < 4 MB).
// ---------------------------------------------------------------------------
__global__ __launch_bounds__(256, 1)
void fused_proposal_vec(const float* __restrict__ gx, const float* __restrict__ gy,
                        const float* __restrict__ Wmux, const float* __restrict__ bmux,
                        const float* __restrict__ Wsgx, const float* __restrict__ bsgx,
                        const float* __restrict__ Wmuy, const float* __restrict__ bmuy,
                        const float* __restrict__ Wsgy, const float* __restrict__ bsgy,
                        float* __restrict__ out)
{
  __shared__ float Xs[16][68];
  __shared__ float Wms[16][132];
  __shared__ float Wss[16][132];
  __shared__ double red[64][8];

  const int tid = threadIdx.x;
  const int tx = tid & 15;
  const int ty = tid >> 4;
  const int r0 = blockIdx.x * 64;
  const int lr = tid >> 2;
  const int q4 = (tid & 3) << 2;

  for (int i = tid; i < 64 * 8; i += 256) ((double*)red)[i] = 0.0;

  for (int ph = 0; ph < 8; ++ph) {
    const int dist = ph >> 2;
    const int c0 = (ph & 3) * 128;
    const float* __restrict__ Xg = dist ? gy : gx;
    const float* __restrict__ Wm = dist ? Wmuy : Wmux;
    const float* __restrict__ Wv = dist ? Wsgy : Wsgx;
    const float* __restrict__ bm = dist ? bmuy : bmux;
    const float* __restrict__ bv = dist ? bsgy : bsgx;

    float am[4][8], av[4][8];
#pragma unroll
    for (int r = 0; r < 4; ++r)
#pragma unroll
      for (int c = 0; c < 8; ++c) { am[r][c] = 0.0f; av[r][c] = 0.0f; }

    const float* xp  = Xg + (size_t)(r0 + lr) * 512 + q4;
    const float* mp0 = Wm + (size_t)(c0 + lr) * 512 + q4;
    const float* mp1 = Wm + (size_t)(c0 + lr + 64) * 512 + q4;
    const float* vp0 = Wv + (size_t)(c0 + lr) * 512 + q4;
    const float* vp1 = Wv + (size_t)(c0 + lr + 64) * 512 + q4;

    float4 xa = *(const float4*)(xp);
    float4 ma = *(const float4*)(mp0);
    float4 mb = *(const float4*)(mp1);
    float4 va = *(const float4*)(vp0);
    float4 vb = *(const float4*)(vp1);

    for (int t = 0; t < 32; ++t) {
      __syncthreads();
#define ST4(arr, col, v) { arr[q4+0][col]=v.x; arr[q4+1][col]=v.y; arr[q4+2][col]=v.z; arr[q4+3][col]=v.w; }
      ST4(Xs,  lr, xa)
      ST4(Wms, lr, ma)  ST4(Wms, lr + 64, mb)
      ST4(Wss, lr, va)  ST4(Wss, lr + 64, vb)
#undef ST4
      __syncthreads();
      if (t + 1 < 32) {
        const int ko = (t + 1) * 16;
        xa = *(const float4*)(xp + ko);
        ma = *(const float4*)(mp0 + ko);
        mb = *(const float4*)(mp1 + ko);
        va = *(const float4*)(vp0 + ko);
        vb = *(const float4*)(vp1 + ko);
      }
#pragma unroll
      for (int kk = 0; kk < 16; ++kk) {
        const float4 x0 = *(const float4*)&Xs[kk][ty * 4];
        const float4 m0 = *(const float4*)&Wms[kk][tx * 4];
        const float4 m1 = *(const float4*)&Wms[kk][tx * 4 + 64];
        const float4 v0 = *(const float4*)&Wss[kk][tx * 4];
        const float4 v1 = *(const float4*)&Wss[kk][tx * 4 + 64];
        const float xr[4] = {x0.x, x0.y, x0.z, x0.w};
        const float wm[8] = {m0.x, m0.y, m0.z, m0.w, m1.x, m1.y, m1.z, m1.w};
        const float wv[8] = {v0.x, v0.y, v0.z, v0.w, v1.x, v1.y, v1.z, v1.w};
#pragma unroll
        for (int r = 0; r < 4; ++r)
#pragma unroll
          for (int c = 0; c < 8; ++c) {
            am[r][c] = fmaf(xr[r], wm[c], am[r][c]);
            av[r][c] = fmaf(xr[r], wv[c], av[r][c]);
          }
      }
    }

    float bmr[8], bvr[8];
#pragma unroll
    for (int c = 0; c < 4; ++c) {
      bmr[c]     = bm[c0 + tx * 4 + c];
      bmr[4 + c] = bm[c0 + 64 + tx * 4 + c];
      bvr[c]     = bv[c0 + tx * 4 + c];
      bvr[4 + c] = bv[c0 + 64 + tx * 4 + c];
    }
#pragma unroll
    for (int r = 0; r < 4; ++r) {
      float pA = 0.f, pI = 0.f, pM = 0.f, pQ = 0.f;
#pragma unroll
      for (int c = 0; c < 8; ++c) {
        const float m = am[r][c] + bmr[c];
        const float s = av[r][c] + bvr[c];
        const float v = fmaxf(expf(s), 1e-6f);
        const float lg = fmaxf(s, LOG_EPS);
        const float inv = __builtin_amdgcn_rcpf(v);
        pA += lg; pI += inv; pM += m * inv; pQ += m * m * inv;
      }
#pragma unroll
      for (int msk = 1; msk < 16; msk <<= 1) {
        pA += __shfl_xor(pA, msk);
        pI += __shfl_xor(pI, msk);
        pM += __shfl_xor(pM, msk);
        pQ += __shfl_xor(pQ, msk);
      }
      if (tx == 0) {
        double* rr = &red[ty * 4 + r][dist * 4];
        rr[0] += (double)pA; rr[1] += (double)pI;
        rr[2] += (double)pM; rr[3] += (double)pQ;
      }
    }
  }

  __syncthreads();

  if (tid < 64) {
    const int grow = r0 + tid;
    const double Ax = red[tid][0], Ix = red[tid][1], Mx = red[tid][2], Qx = red[tid][3];
    const double Ay = red[tid][4], Iy = red[tid][5], My = red[tid][6], Qy = red[tid][7];
    U2 key = tf2x32(0u, 42u, 0u, (uint32_t)grow);
    float xi = 0.0f;
    bool done = false;
    for (int it = 0; it < 100000 && !done; ++it) {
      const U2 kn = tf2x32(key.a, key.b, 0u, 0u);
      const U2 k1 = tf2x32(key.a, key.b, 0u, 1u);
      const U2 k2 = tf2x32(key.a, key.b, 0u, 2u);
      const U2 ru = tf2x32(k1.a, k1.b, 0u, 0u);
      const U2 rx = tf2x32(k2.a, k2.b, 0u, 0u);
      const float u  = bits_to_u01(ru.a ^ ru.b);
      const float u2 = bits_to_u01(rx.a ^ rx.b);
      xi = 2.0f * u2 - 1.0f;
      const double dxi = (double)xi;
      const double nx = (0.5 / 512.0) * (Ax + Qx + dxi * (dxi * Ix - 2.0 * Mx));
      const double ny = (0.5 / 512.0) * (Ay + Qy + dxi * (dxi * Iy - 2.0 * My));
      done = ((double)u >= nx * ny);
      key = kn;
    }
    out[grow] = fminf(fmaxf(xi, 1e-5f), 10.0f);
  }
}

extern "C" void kernel_launch(void* const* d_in, const int* in_sizes, int n_in,
                              void* d_out, int out_size, void* d_ws, size_t ws_size,
                              hipStream_t stream) {
  const float* x    = (const float*)d_in[0];
  const float* y    = (const float*)d_in[1];
  const float* Wmux = (const float*)d_in[2];
  const float* bmux = (const float*)d_in[3];
  const float* Wsgx = (const float*)d_in[4];
  const float* bsgx = (const float*)d_in[5];
  const float* Wmuy = (const float*)d_in[6];
  const float* bmuy = (const float*)d_in[7];
  const float* Wsgy = (const float*)d_in[8];
  const float* bsgy = (const float*)d_in[9];
  (void)in_sizes; (void)n_in; (void)out_size;

  if (ws_size >= (size_t)WS_NEED) {
    convert_w_kernel<<<1024, 256, 0, stream>>>(Wmux, Wsgx, Wmuy, Wsgy, (f16*)d_ws);
    mfma_proposal_kernel<<<512, 256, 0, stream>>>(
        x, y, bmux, bsgx, bmuy, bsgy, (const f16*)d_ws, (float*)d_out);
  } else {
    fused_proposal_vec<<<512, 256, 0, stream>>>(
        x, y, Wmux, bmux, Wsgx, bsgx, Wmuy, bmuy, Wsgy, bsgy, (float*)d_out);
  }
}